// Round 1
// baseline (287.973 us; speedup 1.0000x reference)
//
#include <hip/hip_runtime.h>
#include <math.h>

// Problem constants (fixed by reference)
#define BB 4
#define NN 512
#define DD 128
#define HH 8
#define KK 16

// ---------------------------------------------------------------------------
// Kernel 1: Q/K/V projections.
// Layout choice: store as [b][n][p] with p = h*16 + k (128 floats per token),
// identical layout to an e-row, so the attn kernel can treat K-rows and e-rows
// uniformly. Q is pre-scaled by norm = 1/sqrt(16) = 0.25.
// ---------------------------------------------------------------------------
__global__ __launch_bounds__(128) void proj_kernel(
    const float* __restrict__ q,
    const float* __restrict__ Wq,
    const float* __restrict__ Wk,
    const float* __restrict__ Wv,
    float* __restrict__ Qs,
    float* __restrict__ Kp,
    float* __restrict__ Vp)
{
    __shared__ float qrow[DD];
    const int bn = blockIdx.x;
    const int t = threadIdx.x;          // 0..127 -> p = h*16+k
    qrow[t] = q[(size_t)bn * DD + t];
    __syncthreads();
    const int h = t >> 4;
    const int k = t & 15;
    const float* wq = Wq + (size_t)h * DD * KK + k;   // stride KK over d
    const float* wk = Wk + (size_t)h * DD * KK + k;
    const float* wv = Wv + (size_t)h * DD * KK + k;
    float aq = 0.f, ak = 0.f, av = 0.f;
#pragma unroll 16
    for (int d = 0; d < DD; ++d) {
        const float x = qrow[d];
        aq = fmaf(x, wq[(size_t)d * KK], aq);
        ak = fmaf(x, wk[(size_t)d * KK], ak);
        av = fmaf(x, wv[(size_t)d * KK], av);
    }
    Qs[(size_t)bn * DD + t] = aq * 0.25f;   // norm = 1/sqrt(KEY_DIM=16)
    Kp[(size_t)bn * DD + t] = ak;
    Vp[(size_t)bn * DD + t] = av;
}

// ---------------------------------------------------------------------------
// Kernel 2: fused edge-bias + attention + out-projection.
// One block of 256 threads (4 waves) per output row (b,n).
// m-phase: wave w owns m in [128w, 128w+128), 4 rows per wave-pass.
//   lane: sub = lane>>4 (row in pass), dc = lane&15 (8-float d-chunk).
//   Coalesced float4 loads of e-row and K-row; E_val1 fragment in VGPRs;
//   4-step shfl_xor butterfly within 16-lane groups completes all 8 heads.
// softmax+PV: wave w handles heads 2w, 2w+1. out-proj: threads 0..127.
// ---------------------------------------------------------------------------
__global__ __launch_bounds__(256) void attn_kernel(
    const float* __restrict__ e,
    const float* __restrict__ Ev,      // [H][D]
    const float* __restrict__ Qs,      // [B][N][128], pre-scaled
    const float* __restrict__ Kp,      // [B][N][128]
    const float* __restrict__ Vp,      // [B][N][128]
    const float* __restrict__ Wout,    // [H][16][128] -> [p][e]
    float* __restrict__ out)           // [B][N][128]
{
    __shared__ float comp[HH][NN + 4];   // stride 516 words: write banks 4h+sub, conflict-free
    __shared__ float headsv[HH * KK];

    const int bn   = blockIdx.x;
    const int b    = bn >> 9;            // / NN
    const int tid  = threadIdx.x;
    const int wave = tid >> 6;
    const int lane = tid & 63;
    const int sub  = lane >> 4;          // 0..3 : row within a pass
    const int dc   = lane & 15;          // 8-float chunk
    const int d0   = dc * 8;
    const int myh  = dc >> 1;            // head owning this lane's QK chunk

    // E_val1 fragment: ev[h][j] = Ev[h][d0+j]
    float ev[HH][8];
#pragma unroll
    for (int h = 0; h < HH; ++h) {
        const float4 a = *(const float4*)(Ev + h * DD + d0);
        const float4 c = *(const float4*)(Ev + h * DD + d0 + 4);
        ev[h][0] = a.x; ev[h][1] = a.y; ev[h][2] = a.z; ev[h][3] = a.w;
        ev[h][4] = c.x; ev[h][5] = c.y; ev[h][6] = c.z; ev[h][7] = c.w;
    }
    // Q fragment for this (b,n): positions p = d0..d0+7 (all within head myh)
    float qf[8];
    {
        const float4 a = *(const float4*)(Qs + (size_t)bn * DD + d0);
        const float4 c = *(const float4*)(Qs + (size_t)bn * DD + d0 + 4);
        qf[0] = a.x; qf[1] = a.y; qf[2] = a.z; qf[3] = a.w;
        qf[4] = c.x; qf[5] = c.y; qf[6] = c.z; qf[7] = c.w;
    }

    const float* ebase = e  + (size_t)bn * NN * DD;
    const float* kbase = Kp + (size_t)b  * NN * DD;

    for (int i = 0; i < 32; ++i) {
        const int m = wave * 128 + i * 4 + sub;
        const float* ep  = ebase + (size_t)m * DD + d0;
        const float* kpp = kbase + (size_t)m * DD + d0;
        const float4 e0 = *(const float4*)(ep);
        const float4 e1 = *(const float4*)(ep + 4);
        const float4 k0 = *(const float4*)(kpp);
        const float4 k1 = *(const float4*)(kpp + 4);
        float er[8], kr[8];
        er[0] = e0.x; er[1] = e0.y; er[2] = e0.z; er[3] = e0.w;
        er[4] = e1.x; er[5] = e1.y; er[6] = e1.z; er[7] = e1.w;
        kr[0] = k0.x; kr[1] = k0.y; kr[2] = k0.z; kr[3] = k0.w;
        kr[4] = k1.x; kr[5] = k1.y; kr[6] = k1.z; kr[7] = k1.w;

        float kq = 0.f;
#pragma unroll
        for (int j = 0; j < 8; ++j) kq = fmaf(kr[j], qf[j], kq);

        float acc[HH];
#pragma unroll
        for (int h = 0; h < HH; ++h) {
            float s = (myh == h) ? kq : 0.f;
#pragma unroll
            for (int j = 0; j < 8; ++j) s = fmaf(er[j], ev[h][j], s);
            acc[h] = s;
        }
        // reduce across the 16 lanes sharing this row
#pragma unroll
        for (int mask = 1; mask <= 8; mask <<= 1) {
#pragma unroll
            for (int h = 0; h < HH; ++h)
                acc[h] += __shfl_xor(acc[h], mask);
        }
#pragma unroll
        for (int h = 0; h < HH; ++h)
            if (dc == h) comp[h][m] = acc[h];
    }
    __syncthreads();

    // ---- softmax + PV: wave handles heads 2w, 2w+1 ----
    const float* vbase = Vp + (size_t)b * NN * DD;
#pragma unroll
    for (int hh = 0; hh < 2; ++hh) {
        const int h = wave * 2 + hh;
        float mx = -3.0e38f;
#pragma unroll
        for (int i = 0; i < 8; ++i) mx = fmaxf(mx, comp[h][lane + i * 64]);
#pragma unroll
        for (int mask = 1; mask <= 32; mask <<= 1)
            mx = fmaxf(mx, __shfl_xor(mx, mask));

        float psum = 0.f;
        float av[KK];
#pragma unroll
        for (int v = 0; v < KK; ++v) av[v] = 0.f;
#pragma unroll
        for (int i = 0; i < 8; ++i) {
            const int m = lane + i * 64;
            const float p = __expf(comp[h][m] - mx);
            psum += p;
            const float* vp = vbase + (size_t)m * DD + h * KK;
            const float4 v0 = *(const float4*)(vp);
            const float4 v1 = *(const float4*)(vp + 4);
            const float4 v2 = *(const float4*)(vp + 8);
            const float4 v3 = *(const float4*)(vp + 12);
            av[0]  = fmaf(p, v0.x, av[0]);  av[1]  = fmaf(p, v0.y, av[1]);
            av[2]  = fmaf(p, v0.z, av[2]);  av[3]  = fmaf(p, v0.w, av[3]);
            av[4]  = fmaf(p, v1.x, av[4]);  av[5]  = fmaf(p, v1.y, av[5]);
            av[6]  = fmaf(p, v1.z, av[6]);  av[7]  = fmaf(p, v1.w, av[7]);
            av[8]  = fmaf(p, v2.x, av[8]);  av[9]  = fmaf(p, v2.y, av[9]);
            av[10] = fmaf(p, v2.z, av[10]); av[11] = fmaf(p, v2.w, av[11]);
            av[12] = fmaf(p, v3.x, av[12]); av[13] = fmaf(p, v3.y, av[13]);
            av[14] = fmaf(p, v3.z, av[14]); av[15] = fmaf(p, v3.w, av[15]);
        }
#pragma unroll
        for (int mask = 1; mask <= 32; mask <<= 1) {
            psum += __shfl_xor(psum, mask);
#pragma unroll
            for (int v = 0; v < KK; ++v) av[v] += __shfl_xor(av[v], mask);
        }
        if (lane == 0) {
            const float inv = 1.f / psum;
#pragma unroll
            for (int v = 0; v < KK; ++v) headsv[h * KK + v] = av[v] * inv;
        }
    }
    __syncthreads();

    // ---- out projection: out[bn][t] = sum_p headsv[p] * Wout[p][t] ----
    if (tid < DD) {
        float o = 0.f;
#pragma unroll 8
        for (int p = 0; p < HH * KK; ++p)
            o = fmaf(headsv[p], Wout[(size_t)p * DD + tid], o);
        out[(size_t)bn * DD + tid] = o;
    }
}

extern "C" void kernel_launch(void* const* d_in, const int* in_sizes, int n_in,
                              void* d_out, int out_size, void* d_ws, size_t ws_size,
                              hipStream_t stream) {
    const float* q    = (const float*)d_in[0];
    const float* e    = (const float*)d_in[1];
    const float* Wq   = (const float*)d_in[2];
    const float* Wk   = (const float*)d_in[3];
    const float* Wv   = (const float*)d_in[4];
    const float* Ev   = (const float*)d_in[5];
    const float* Wout = (const float*)d_in[6];
    float* out = (float*)d_out;

    float* Qs = (float*)d_ws;                 // [B][N][128]
    float* Kp = Qs + (size_t)BB * NN * DD;    // [B][N][128]
    float* Vp = Kp + (size_t)BB * NN * DD;    // [B][N][128]

    proj_kernel<<<BB * NN, 128, 0, stream>>>(q, Wq, Wk, Wv, Qs, Kp, Vp);
    attn_kernel<<<BB * NN, 256, 0, stream>>>(e, Ev, Qs, Kp, Vp, Wout, out);
}

// Round 2
// 222.510 us; speedup vs baseline: 1.2942x; 1.2942x over previous
//
#include <hip/hip_runtime.h>
#include <math.h>

// Problem constants (fixed by reference)
#define BB 4
#define NN 512
#define DD 128
#define HH 8
#define KK 16

// ---------------------------------------------------------------------------
// Kernel 1: Q/K/V projections (unchanged, verified round 1).
// Store as [b][n][p] with p = h*16 + k; Q pre-scaled by 1/sqrt(16) = 0.25.
// ---------------------------------------------------------------------------
__global__ __launch_bounds__(128) void proj_kernel(
    const float* __restrict__ q,
    const float* __restrict__ Wq,
    const float* __restrict__ Wk,
    const float* __restrict__ Wv,
    float* __restrict__ Qs,
    float* __restrict__ Kp,
    float* __restrict__ Vp)
{
    __shared__ float qrow[DD];
    const int bn = blockIdx.x;
    const int t = threadIdx.x;          // 0..127 -> p = h*16+k
    qrow[t] = q[(size_t)bn * DD + t];
    __syncthreads();
    const int h = t >> 4;
    const int k = t & 15;
    const float* wq = Wq + (size_t)h * DD * KK + k;   // stride KK over d
    const float* wk = Wk + (size_t)h * DD * KK + k;
    const float* wv = Wv + (size_t)h * DD * KK + k;
    float aq = 0.f, ak = 0.f, av = 0.f;
#pragma unroll 16
    for (int d = 0; d < DD; ++d) {
        const float x = qrow[d];
        aq = fmaf(x, wq[(size_t)d * KK], aq);
        ak = fmaf(x, wk[(size_t)d * KK], ak);
        av = fmaf(x, wv[(size_t)d * KK], av);
    }
    Qs[(size_t)bn * DD + t] = aq * 0.25f;   // norm = 1/sqrt(KEY_DIM=16)
    Kp[(size_t)bn * DD + t] = ak;
    Vp[(size_t)bn * DD + t] = av;
}

// ---------------------------------------------------------------------------
// Kernel 2: fused edge-bias + attention + out-projection.
// Round-2 change: shuffle-FOLD reductions instead of full butterflies.
//   m-phase DS ops/iter: 72 -> 9 (8 shfl + 1 conflict-free ds_write).
//   After the fold, lane dc holds head h = dc>>1 (dc even writes comp[h][m]).
//   softmax av[16] reduce: 96 shfl -> 17 shfl fold; lane (lane&3)==0 owns
//   v = lane>>2 and writes headsv.
// ---------------------------------------------------------------------------
__global__ __launch_bounds__(256) void attn_kernel(
    const float* __restrict__ e,
    const float* __restrict__ Ev,      // [H][D]
    const float* __restrict__ Qs,      // [B][N][128], pre-scaled
    const float* __restrict__ Kp,      // [B][N][128]
    const float* __restrict__ Vp,      // [B][N][128]
    const float* __restrict__ Wout,    // [H*16][128] -> [p][e]
    float* __restrict__ out)           // [B][N][128]
{
    __shared__ float comp[HH][NN + 4];   // stride 516: phase-1 write banks 4h+sub+m, all 32 distinct
    __shared__ float headsv[HH * KK];

    const int bn   = blockIdx.x;
    const int b    = bn >> 9;            // / NN
    const int tid  = threadIdx.x;
    const int wave = tid >> 6;
    const int lane = tid & 63;
    const int sub  = lane >> 4;          // 0..3 : row within a pass
    const int dc   = lane & 15;          // 8-float chunk
    const int d0   = dc * 8;
    const int myh  = dc >> 1;            // head owning this lane's QK chunk

    // E_val1 fragment: ev[h][j] = Ev[h][d0+j]
    float ev[HH][8];
#pragma unroll
    for (int h = 0; h < HH; ++h) {
        const float4 a = *(const float4*)(Ev + h * DD + d0);
        const float4 c = *(const float4*)(Ev + h * DD + d0 + 4);
        ev[h][0] = a.x; ev[h][1] = a.y; ev[h][2] = a.z; ev[h][3] = a.w;
        ev[h][4] = c.x; ev[h][5] = c.y; ev[h][6] = c.z; ev[h][7] = c.w;
    }
    // Q fragment for this (b,n): positions p = d0..d0+7 (all within head myh)
    float qf[8];
    {
        const float4 a = *(const float4*)(Qs + (size_t)bn * DD + d0);
        const float4 c = *(const float4*)(Qs + (size_t)bn * DD + d0 + 4);
        qf[0] = a.x; qf[1] = a.y; qf[2] = a.z; qf[3] = a.w;
        qf[4] = c.x; qf[5] = c.y; qf[6] = c.z; qf[7] = c.w;
    }

    const float* ebase = e  + (size_t)bn * NN * DD;
    const float* kbase = Kp + (size_t)b  * NN * DD;

    for (int i = 0; i < 32; ++i) {
        const int m = wave * 128 + i * 4 + sub;
        const float* ep  = ebase + (size_t)m * DD + d0;
        const float* kpp = kbase + (size_t)m * DD + d0;
        const float4 e0 = *(const float4*)(ep);
        const float4 e1 = *(const float4*)(ep + 4);
        const float4 k0 = *(const float4*)(kpp);
        const float4 k1 = *(const float4*)(kpp + 4);
        float er[8], kr[8];
        er[0] = e0.x; er[1] = e0.y; er[2] = e0.z; er[3] = e0.w;
        er[4] = e1.x; er[5] = e1.y; er[6] = e1.z; er[7] = e1.w;
        kr[0] = k0.x; kr[1] = k0.y; kr[2] = k0.z; kr[3] = k0.w;
        kr[4] = k1.x; kr[5] = k1.y; kr[6] = k1.z; kr[7] = k1.w;

        float kq = 0.f;
#pragma unroll
        for (int j = 0; j < 8; ++j) kq = fmaf(kr[j], qf[j], kq);

        float acc[HH];
#pragma unroll
        for (int h = 0; h < HH; ++h) {
            float s = (myh == h) ? kq : 0.f;
#pragma unroll
            for (int j = 0; j < 8; ++j) s = fmaf(er[j], ev[h][j], s);
            acc[h] = s;
        }

        // ---- fold reduction across the 16 lanes sharing row m ----
        // step 1: 8 values -> 4 (partner lane^8)
        const bool hi8 = (dc & 8) != 0;
        float t4[4];
#pragma unroll
        for (int j = 0; j < 4; ++j) {
            const float keep = hi8 ? acc[j + 4] : acc[j];
            const float send = hi8 ? acc[j]     : acc[j + 4];
            t4[j] = keep + __shfl_xor(send, 8);
        }
        // step 2: 4 -> 2 (partner lane^4)
        const bool hi4 = (dc & 4) != 0;
        float t2[2];
#pragma unroll
        for (int j = 0; j < 2; ++j) {
            const float keep = hi4 ? t2[0]*0.f + t4[j + 2] : t4[j];
            const float send = hi4 ? t4[j]     : t4[j + 2];
            t2[j] = keep + __shfl_xor(send, 4);
        }
        // step 3: 2 -> 1 (partner lane^2)
        const bool hi2 = (dc & 2) != 0;
        float w;
        {
            const float keep = hi2 ? t2[1] : t2[0];
            const float send = hi2 ? t2[0] : t2[1];
            w = keep + __shfl_xor(send, 2);
        }
        // step 4: complete over lane^1; lane dc now holds head dc>>1
        w += __shfl_xor(w, 1);
        if ((dc & 1) == 0) comp[dc >> 1][m] = w;
    }
    __syncthreads();

    // ---- softmax + PV: wave handles heads 2w, 2w+1 ----
    const float* vbase = Vp + (size_t)b * NN * DD;
#pragma unroll
    for (int hh = 0; hh < 2; ++hh) {
        const int h = wave * 2 + hh;
        float mx = -3.0e38f;
#pragma unroll
        for (int i = 0; i < 8; ++i) mx = fmaxf(mx, comp[h][lane + i * 64]);
#pragma unroll
        for (int mask = 1; mask <= 32; mask <<= 1)
            mx = fmaxf(mx, __shfl_xor(mx, mask));

        float psum = 0.f;
        float av[KK];
#pragma unroll
        for (int v = 0; v < KK; ++v) av[v] = 0.f;
#pragma unroll
        for (int i = 0; i < 8; ++i) {
            const int m = lane + i * 64;
            const float p = __expf(comp[h][m] - mx);
            psum += p;
            const float* vp = vbase + (size_t)m * DD + h * KK;
            const float4 v0 = *(const float4*)(vp);
            const float4 v1 = *(const float4*)(vp + 4);
            const float4 v2 = *(const float4*)(vp + 8);
            const float4 v3 = *(const float4*)(vp + 12);
            av[0]  = fmaf(p, v0.x, av[0]);  av[1]  = fmaf(p, v0.y, av[1]);
            av[2]  = fmaf(p, v0.z, av[2]);  av[3]  = fmaf(p, v0.w, av[3]);
            av[4]  = fmaf(p, v1.x, av[4]);  av[5]  = fmaf(p, v1.y, av[5]);
            av[6]  = fmaf(p, v1.z, av[6]);  av[7]  = fmaf(p, v1.w, av[7]);
            av[8]  = fmaf(p, v2.x, av[8]);  av[9]  = fmaf(p, v2.y, av[9]);
            av[10] = fmaf(p, v2.z, av[10]); av[11] = fmaf(p, v2.w, av[11]);
            av[12] = fmaf(p, v3.x, av[12]); av[13] = fmaf(p, v3.y, av[13]);
            av[14] = fmaf(p, v3.z, av[14]); av[15] = fmaf(p, v3.w, av[15]);
        }
        // psum: full butterfly (all lanes need it)
#pragma unroll
        for (int mask = 1; mask <= 32; mask <<= 1)
            psum += __shfl_xor(psum, mask);

        // av[16] fold over 64 lanes: v index bits come from lane bits 5..2
        const bool s5 = (lane & 32) != 0;
        float a8[8];
#pragma unroll
        for (int j = 0; j < 8; ++j) {
            const float keep = s5 ? av[j + 8] : av[j];
            const float send = s5 ? av[j]     : av[j + 8];
            a8[j] = keep + __shfl_xor(send, 32);
        }
        const bool s4 = (lane & 16) != 0;
        float a4[4];
#pragma unroll
        for (int j = 0; j < 4; ++j) {
            const float keep = s4 ? a8[j + 4] : a8[j];
            const float send = s4 ? a8[j]     : a8[j + 4];
            a4[j] = keep + __shfl_xor(send, 16);
        }
        const bool s3 = (lane & 8) != 0;
        float a2[2];
#pragma unroll
        for (int j = 0; j < 2; ++j) {
            const float keep = s3 ? a4[j + 2] : a4[j];
            const float send = s3 ? a4[j]     : a4[j + 2];
            a2[j] = keep + __shfl_xor(send, 8);
        }
        const bool s2 = (lane & 4) != 0;
        float a1;
        {
            const float keep = s2 ? a2[1] : a2[0];
            const float send = s2 ? a2[0] : a2[1];
            a1 = keep + __shfl_xor(send, 4);
        }
        a1 += __shfl_xor(a1, 2);
        a1 += __shfl_xor(a1, 1);
        if ((lane & 3) == 0)
            headsv[h * KK + (lane >> 2)] = a1 / psum;
    }
    __syncthreads();

    // ---- out projection: out[bn][t] = sum_p headsv[p] * Wout[p][t] ----
    if (tid < DD) {
        float o = 0.f;
#pragma unroll 8
        for (int p = 0; p < HH * KK; ++p)
            o = fmaf(headsv[p], Wout[(size_t)p * DD + tid], o);
        out[(size_t)bn * DD + tid] = o;
    }
}

extern "C" void kernel_launch(void* const* d_in, const int* in_sizes, int n_in,
                              void* d_out, int out_size, void* d_ws, size_t ws_size,
                              hipStream_t stream) {
    const float* q    = (const float*)d_in[0];
    const float* e    = (const float*)d_in[1];
    const float* Wq   = (const float*)d_in[2];
    const float* Wk   = (const float*)d_in[3];
    const float* Wv   = (const float*)d_in[4];
    const float* Ev   = (const float*)d_in[5];
    const float* Wout = (const float*)d_in[6];
    float* out = (float*)d_out;

    float* Qs = (float*)d_ws;                 // [B][N][128]
    float* Kp = Qs + (size_t)BB * NN * DD;    // [B][N][128]
    float* Vp = Kp + (size_t)BB * NN * DD;    // [B][N][128]

    proj_kernel<<<BB * NN, 128, 0, stream>>>(q, Wq, Wk, Wv, Qs, Kp, Vp);
    attn_kernel<<<BB * NN, 256, 0, stream>>>(e, Ev, Qs, Kp, Vp, Wout, out);
}